// Round 3
// baseline (273.375 us; speedup 1.0000x reference)
//
#include <hip/hip_runtime.h>
#include <math.h>

// ReAttention round 7c: round-7 kernel, cvt_pkrtz type fix (__fp16 vec2).
//  - sU double-buffered -> ONE barrier/it (was 2): mix(VALU) of it+1 overlaps
//    PV(MFMA) of it across waves; vT loads hoisted above the barrier so L2
//    latency drains under the barrier wait.
//  - mix: e pre-scaled by rv in packed f16 (v_pk_mul_f16), accumulate f32 via
//    (float)half * sgpr_cw fma (-> v_fma_mix_f32), pack with cvt_pkrtz.
//  - su dropped: E[u_g] = sum_h cw[g,h]/N analytically (softmax rows sum to 1);
//    k_alpha computes the mean from conv_w. Only su2 accumulated.
//  - R5 lesson: keep live set small, cap (512,2). Peak live ~98 VGPR.
// B=8 N=1024 D=512 H=8 dh=64.
//
//  - conv bias cancels in train-mode BN (shifts mean only).
//  - attn'' = alpha_g*u_g + c_g ; u_g = sum_h conv_w[g,h]*S_h
//  - out_inner = alpha_g*O1 + c_g*vsum ; O1 = u @ v  (alpha-independent)
//  - S~ stored UNNORMALIZED fp16, head-interleaved: el ((b*N+n)*N+m)*8+h

#define Bz 8
#define Nn 1024
#define Dd 512
#define Hh 8
#define DH 64
#define INNER 512
#define QW 1536
#define SCALE 0.125f
#define BN_EPS 1e-5f

typedef _Float16 __f16;
typedef __f16 f16x8 __attribute__((ext_vector_type(8)));
typedef __f16 f16x2 __attribute__((ext_vector_type(2)));
typedef __fp16 fp16x2 __attribute__((ext_vector_type(2)));  // cvt_pkrtz return type
typedef float f32x4 __attribute__((ext_vector_type(4)));

#define MFMA16(a, b, c) __builtin_amdgcn_mfma_f32_16x16x32_f16((a), (b), (c), 0, 0, 0)

__device__ __forceinline__ unsigned short f2h(float f) {
  union { __f16 h; unsigned short s; } v;
  v.h = (__f16)f;  // v_cvt_f16_f32, RTN
  return v.s;
}
__device__ __forceinline__ float h2f(unsigned short s) {
  union { unsigned short s; __f16 h; } v;
  v.s = s;
  return (float)v.h;
}

// ws layout (bytes)
#define WB_XB 0u                       // 8,388,608  x fp16
#define WB_QKV 8388608u                // 25,165,824 q,k fp16 (stride QW)
#define WB_O1 0u                       // 16,777,216 fp32 (overlays XB + head of QKV; both dead)
#define WB_VT 33554432u                // 8,388,608  v^T fp16 [b,g,d,m]
#define WB_SG 41943040u                // 134,217,728 S~ fp16 [b,n,m,h]
#define WB_O1BF WB_SG                  // 8,388,608 fp16, overlays dead S~
#define WB_WQT 176160768u              // 1,572,864
#define WB_WOT 177733632u              // 524,288
#define WB_RSUM 178257920u             // 262,144
#define WB_VSUM 178520064u             // 16,384
#define WB_STATS 178536448u            // 64
#define WB_AC 178536512u               // 64

// ---------------- x -> fp16 ------------------------------------------------
__global__ __launch_bounds__(256) void k_xbf(const float* __restrict__ X,
                                             unsigned short* __restrict__ XB) {
  const size_t i = ((size_t)blockIdx.x * 256 + threadIdx.x) * 8;
  float4 f0 = *(const float4*)(X + i);
  float4 f1 = *(const float4*)(X + i + 4);
  unsigned short o[8] = {f2h(f0.x), f2h(f0.y), f2h(f0.z), f2h(f0.w),
                         f2h(f1.x), f2h(f1.y), f2h(f1.z), f2h(f1.w)};
  *(uint4*)(XB + i) = *(uint4*)o;
}

// ---------------- transpose fp32 -> fp16: dst[C][R] = src[R][C]^T ----------
__global__ __launch_bounds__(256) void k_transpose(const float* __restrict__ src,
                                                   unsigned short* __restrict__ dst,
                                                   int R, int C) {
  __shared__ float tile[32][33];
  const int tc = blockIdx.x * 32, tr = blockIdx.y * 32;
  const int lx = threadIdx.x & 31, ly = threadIdx.x >> 5;
#pragma unroll
  for (int i = 0; i < 32; i += 8)
    tile[ly + i][lx] = src[(size_t)(tr + ly + i) * C + tc + lx];
  __syncthreads();
#pragma unroll
  for (int i = 0; i < 32; i += 8)
    dst[(size_t)(tc + ly + i) * R + tr + lx] = f2h(tile[lx][ly + i]);
}

// ---------------- K0: qkv = x @ w_qkv (fp16 MFMA) --------------------------
__global__ __launch_bounds__(256) void k_qkv(const unsigned short* __restrict__ XB,
                                             const unsigned short* __restrict__ WQT,
                                             unsigned short* __restrict__ qkv,
                                             unsigned short* __restrict__ vT) {
  extern __shared__ char smem[];
  unsigned short(*sA)[40] = (unsigned short(*)[40])smem;
  unsigned short(*sB)[40] = (unsigned short(*)[40])(smem + 128 * 40 * 2);
  unsigned short* sEp = (unsigned short*)smem;  // 128*136 after loop
  const int t = threadIdx.x;
  const int col0 = blockIdx.x * 128;
  const int row0 = blockIdx.y * 128;
  const bool isqk = (col0 < 2 * INNER);
  const int l = t & 63, w = t >> 6;
  const int wm = (w & 1) * 64, wn = (w >> 1) * 64;
  const int lm = l & 15, lq = l >> 4;
  const int srow = t >> 1, skc = (t & 1) * 16;
  f32x4 acc[4][4] = {};
  for (int k0 = 0; k0 < Dd; k0 += 32) {
    {
      const unsigned short* src = XB + (size_t)(row0 + srow) * Dd + k0 + skc;
      *(uint4*)&sA[srow][skc] = *(const uint4*)src;
      *(uint4*)&sA[srow][skc + 8] = *(const uint4*)(src + 8);
    }
    {
      const unsigned short* srcB = WQT + (size_t)(col0 + srow) * Dd + k0 + skc;
      *(uint4*)&sB[srow][skc] = *(const uint4*)srcB;
      *(uint4*)&sB[srow][skc + 8] = *(const uint4*)(srcB + 8);
    }
    __syncthreads();
    f16x8 af[4], bfr[4];
#pragma unroll
    for (int i = 0; i < 4; i++) af[i] = *(const f16x8*)&sA[wm + 16 * i + lm][lq * 8];
#pragma unroll
    for (int j = 0; j < 4; j++) bfr[j] = *(const f16x8*)&sB[wn + 16 * j + lm][lq * 8];
    if (isqk) {
#pragma unroll
      for (int i = 0; i < 4; i++)
#pragma unroll
        for (int j = 0; j < 4; j++) acc[i][j] = MFMA16(bfr[i], af[j], acc[i][j]);
    } else {
#pragma unroll
      for (int i = 0; i < 4; i++)
#pragma unroll
        for (int j = 0; j < 4; j++) acc[i][j] = MFMA16(af[i], bfr[j], acc[i][j]);
    }
    __syncthreads();
  }
  if (isqk) {
#pragma unroll
    for (int jc = 0; jc < 4; jc++)
#pragma unroll
      for (int ir = 0; ir < 4; ir++) {
        unsigned short us[4];
#pragma unroll
        for (int r = 0; r < 4; r++) us[r] = f2h(acc[jc][ir][r]);
        *(uint2*)&sEp[(wm + 16 * ir + lm) * 136 + wn + 16 * jc + 4 * lq] = *(uint2*)us;
      }
    __syncthreads();
    const int row = t >> 1, half = t & 1;
    const unsigned short* src = &sEp[row * 136 + half * 64];
    unsigned short* dst = qkv + (size_t)(row0 + row) * QW + col0 + half * 64;
#pragma unroll
    for (int c = 0; c < 8; c++) *(uint4*)(dst + c * 8) = *(const uint4*)(src + c * 8);
  } else {
#pragma unroll
    for (int ir = 0; ir < 4; ir++)
#pragma unroll
      for (int jc = 0; jc < 4; jc++) {
        unsigned short us[4];
#pragma unroll
        for (int r = 0; r < 4; r++) us[r] = f2h(acc[ir][jc][r]);
        *(uint2*)&sEp[(wn + 16 * jc + lm) * 136 + wm + 16 * ir + 4 * lq] = *(uint2*)us;
      }
    __syncthreads();
    const int row = t >> 1, half = t & 1;
    const int gd = col0 - 2 * INNER + row;
    const int bq = row0 >> 10, mseq0 = row0 & 1023;
    const unsigned short* src = &sEp[row * 136 + half * 64];
    unsigned short* dst =
        vT + (((size_t)(bq * Hh + (gd >> 6)) * DH + (gd & 63)) << 10) + mseq0 + half * 64;
#pragma unroll
    for (int c = 0; c < 8; c++) *(uint4*)(dst + c * 8) = *(const uint4*)(src + c * 8);
  }
}

// ---------------- k_vsum --------------------------------------------------
__global__ __launch_bounds__(256) void k_vsum(const unsigned short* __restrict__ vT,
                                              float* __restrict__ vsum) {
  const int bg = blockIdx.x;
  const int d = threadIdx.x >> 2, qq = threadIdx.x & 3;
  __shared__ float red[64][4];
  const unsigned short* p = vT + ((size_t)bg * DH + d) * Nn + qq * 256;
  float s = 0.f;
  for (int m = 0; m < 256; m += 4) {
    uint2 rr = *(const uint2*)(p + m);
    s += h2f((unsigned short)(rr.x & 0xffff)) + h2f((unsigned short)(rr.x >> 16)) +
         h2f((unsigned short)(rr.y & 0xffff)) + h2f((unsigned short)(rr.y >> 16));
  }
  red[d][qq] = s;
  __syncthreads();
  if (threadIdx.x < 64)
    vsum[(size_t)bg * DH + threadIdx.x] =
        red[threadIdx.x][0] + red[threadIdx.x][1] + red[threadIdx.x][2] + red[threadIdx.x][3];
}

// ---------------- kA: S~ head-interleaved + row-sum partials ---------------
// grid (b=8, nt=32, mh=2); block 512 = 8 waves, wave w = head w.
__global__ __launch_bounds__(512, 2) void k_sgen(const unsigned short* __restrict__ qkv,
                                                 unsigned short* __restrict__ Sg,
                                                 float* __restrict__ rsum) {
  __shared__ unsigned short sK[8 * 32 * 72];  // 36,864 B
  __shared__ unsigned short sT[32 * 264];     // 16,896 B  [n][m*8+h], pad 8
  const int b = blockIdx.x;
  const int n0 = blockIdx.y * 32;
  const int mh = blockIdx.z;
  const int t = threadIdx.x;
  const int w = t >> 6, l = t & 63;
  const int lm = l & 15, lq = l >> 4;
  f16x8 qf[2][2];
#pragma unroll
  for (int i = 0; i < 2; i++) {
    const unsigned short* qp =
        qkv + (size_t)(b * Nn + n0 + 16 * i + lm) * QW + w * DH + lq * 8;
    qf[i][0] = *(const f16x8*)qp;
    qf[i][1] = *(const f16x8*)(qp + 32);
  }
  float psum[2] = {0.f, 0.f};
  for (int it = 0; it < 16; it++) {
    const int m0 = mh * 512 + it * 32;
    {  // stage K: all heads, 32m x 64d, [h][m][72]; uint4 = 8 shorts
#pragma unroll
      for (int s = 0; s < 4; s++) {
        const int c = t + s * 512;
        const int hh = c >> 8, mm = (c >> 3) & 31, qq = c & 7;
        *(uint4*)&sK[(hh * 32 + mm) * 72 + qq * 8] = *(const uint4*)(
            qkv + (size_t)(b * Nn + m0 + mm) * QW + INNER + hh * DH + qq * 8);
      }
    }
    __syncthreads();
    f32x4 lac[2][2] = {};
#pragma unroll
    for (int jm = 0; jm < 2; jm++) {
      f16x8 ka0 = *(const f16x8*)&sK[(w * 32 + 16 * jm + lm) * 72 + lq * 8];
      f16x8 ka1 = *(const f16x8*)&sK[(w * 32 + 16 * jm + lm) * 72 + 32 + lq * 8];
#pragma unroll
      for (int i = 0; i < 2; i++) {
        lac[i][jm] = MFMA16(ka0, qf[i][0], lac[i][jm]);
        lac[i][jm] = MFMA16(ka1, qf[i][1], lac[i][jm]);
      }
    }
#pragma unroll
    for (int i = 0; i < 2; i++)
#pragma unroll
      for (int jm = 0; jm < 2; jm++)
#pragma unroll
        for (int r = 0; r < 4; r++) {
          float e = __expf(lac[i][jm][r] * SCALE);
          psum[i] += e;
          sT[(16 * i + lm) * 264 + (16 * jm + 4 * lq + r) * 8 + w] = f2h(e);
        }
    __syncthreads();
    {  // coop store: 32 rows x 512B, fully coalesced
      const int row = t >> 4, ck = t & 15;
      unsigned short* dst =
          Sg + (((size_t)(b * Nn + n0 + row) << 10) + m0) * 8 + ck * 16;
      const unsigned short* src = &sT[row * 264 + ck * 16];
      *(uint4*)dst = *(const uint4*)src;
      *(uint4*)(dst + 8) = *(const uint4*)(src + 8);
    }
  }
#pragma unroll
  for (int i = 0; i < 2; i++) {
    psum[i] += __shfl_xor(psum[i], 16);
    psum[i] += __shfl_xor(psum[i], 32);
  }
  if (lq == 0) {
    atomicAdd(&rsum[(size_t)(b * Hh + w) * Nn + n0 + lm], psum[0]);
    atomicAdd(&rsum[(size_t)(b * Hh + w) * Nn + n0 + 16 + lm], psum[1]);
  }
}

// ---------------- kB: mix + stats + S@V (dbuf sU, 1 barrier/it) ------------
// grid (b=8, nt=64); block 512 = 8 waves; wave w = group g.
// su dropped (analytic mean in k_alpha); su2 via 2 fma/g; mix in f32 accum
// from packed-f16 e*rv (v_pk_mul) with (float)half * sgpr_cw -> v_fma_mix.
__global__ __launch_bounds__(512, 2) void k_mixsv(const unsigned short* __restrict__ Sg,
                                                  const unsigned short* __restrict__ vT,
                                                  const float* __restrict__ rsum,
                                                  const float* __restrict__ conv_w,
                                                  float* __restrict__ O1,
                                                  float* __restrict__ stats) {
  __shared__ unsigned short sU[2][8][16][68];  // 34,816 B double-buffered
  __shared__ float sRed[8][8];
  const int b = blockIdx.x;  // b fastest -> XCD-pinned vT slice in L2
  const int n0 = blockIdx.y * 16;
  const int t = threadIdx.x;
  const int w = t >> 6, l = t & 63;
  const int lm = l & 15, lq = l >> 4;
  const int mxn = t >> 5, mxm = (t & 31) * 2;
  float cw[64];
#pragma unroll
  for (int i = 0; i < 64; i++) cw[i] = conv_w[i];  // uniform -> SGPRs
  // rv packed f16 per h-pair (n fixed per thread -> loop-invariant)
  f16x2 rvh2[4];
#pragma unroll
  for (int hp = 0; hp < 4; hp++) {
    float r0 = 1.0f / rsum[(size_t)(b * Hh + 2 * hp) * Nn + n0 + mxn];
    float r1 = 1.0f / rsum[(size_t)(b * Hh + 2 * hp + 1) * Nn + n0 + mxn];
    f16x2 rr;
    rr[0] = (__f16)r0;
    rr[1] = (__f16)r1;
    rvh2[hp] = rr;
  }
  const unsigned short* sNp = Sg + ((size_t)(b * Nn + n0 + mxn) << 13);  // row base *8192
  f32x4 oacc[4] = {};
  float su2[8] = {};
  uint4 c0, c1;
  {
    const unsigned short* p = sNp + (mxm << 3);
    c0 = *(const uint4*)p;
    c1 = *(const uint4*)(p + 8);
  }
  int p = 0;
  for (int it = 0; it < 16; it++) {
    uint4 nx0, nx1;
    if (it < 15) {  // shallow prefetch (2 uint4 live extra — no spill at cap 256)
      const unsigned short* pp = sNp + ((size_t)((it + 1) * 64 + mxm) << 3);
      nx0 = *(const uint4*)pp;
      nx1 = *(const uint4*)(pp + 8);
    }
    {  // mix: 2 m-positions x 8 heads from c0/c1
      const f16x2* pe2 = (const f16x2*)&c0;  // m even, h-pairs 0..3
      const f16x2* po2 = (const f16x2*)&c1;  // m odd
      f16x2 eh[4], oh[4];
#pragma unroll
      for (int hp = 0; hp < 4; hp++) {  // v_pk_mul_f16: e*rv packed
        eh[hp] = pe2[hp] * rvh2[hp];
        oh[hp] = po2[hp] * rvh2[hp];
      }
#pragma unroll
      for (int g = 0; g < 8; g++) {
        float u0 = 0.f, u1 = 0.f;
#pragma unroll
        for (int hp = 0; hp < 4; hp++) {  // (float)f16 * sgpr -> v_fma_mix_f32
          u0 = fmaf((float)eh[hp][0], cw[g * 8 + 2 * hp], u0);
          u0 = fmaf((float)eh[hp][1], cw[g * 8 + 2 * hp + 1], u0);
          u1 = fmaf((float)oh[hp][0], cw[g * 8 + 2 * hp], u1);
          u1 = fmaf((float)oh[hp][1], cw[g * 8 + 2 * hp + 1], u1);
        }
        su2[g] = fmaf(u0, u0, fmaf(u1, u1, su2[g]));
        fp16x2 pk = __builtin_amdgcn_cvt_pkrtz(u0, u1);
        *(unsigned*)&sU[p][g][mxn][mxm] = *(unsigned*)&pk;
      }
    }
    // vT loads for THIS it: no sU dependency — issue before the barrier so
    // L2 latency drains under the barrier wait.
    f16x8 va[4], vb[4];
#pragma unroll
    for (int j = 0; j < 4; j++) {
      const unsigned short* vp =
          vT + (((size_t)(b * Hh + w) * DH + 16 * j + lm) << 10) + it * 64 + lq * 8;
      va[j] = *(const f16x8*)vp;
      vb[j] = *(const f16x8*)(vp + 32);
    }
    __syncthreads();  // sU[p] ready; dbuf makes this the ONLY barrier needed:
                      // PV-read(p)@it precedes any mix-write(p)@it+2 via barrier@it+1.
    {  // S@V for group w: A = sU[p][w], B = vT (prefetched regs)
      f16x8 uf0 = *(const f16x8*)&sU[p][w][lm][lq * 8];
      f16x8 uf1 = *(const f16x8*)&sU[p][w][lm][32 + lq * 8];
#pragma unroll
      for (int j = 0; j < 4; j++) {
        oacc[j] = MFMA16(uf0, va[j], oacc[j]);
        oacc[j] = MFMA16(uf1, vb[j], oacc[j]);
      }
    }
    if (it < 15) {
      c0 = nx0;
      c1 = nx1;
    }
    p ^= 1;
  }
#pragma unroll
  for (int j = 0; j < 4; j++)
#pragma unroll
    for (int r = 0; r < 4; r++)
      O1[((size_t)(b * Hh + w) * Nn + n0 + lq * 4 + r) * DH + 16 * j + lm] = oacc[j][r];
#pragma unroll
  for (int g = 0; g < 8; g++) {
    float q = su2[g];
    for (int off = 32; off; off >>= 1) q += __shfl_down(q, off);
    if (l == 0) sRed[w][g] = q;
  }
  __syncthreads();
  if (t < 8) {
    float s = 0.f;
#pragma unroll
    for (int ww = 0; ww < 8; ww++) s += sRed[ww][t];
    atomicAdd(&stats[8 + t], s);
  }
}

// ---------------- K3: alpha/const ------------------------------------------
// E[u_g] analytic: softmax rows sum to 1 -> mean = sum_h cw[g,h] / N.
__global__ void k_alpha(const float* __restrict__ stats, const float* __restrict__ conv_w,
                        const float* __restrict__ bn_gamma,
                        const float* __restrict__ bn_beta, float* __restrict__ ac) {
  const int g = threadIdx.x;
  if (g < 8) {
    const float cnt = (float)Bz * (float)Nn * (float)Nn;
    float sc = 0.f;
#pragma unroll
    for (int h = 0; h < 8; h++) sc += conv_w[g * 8 + h];
    float Eu = sc * (1.0f / (float)Nn);
    float Eu2 = stats[8 + g] / cnt;
    float inv = rsqrtf(Eu2 - Eu * Eu + BN_EPS);
    float alpha = bn_gamma[g] * inv;
    ac[g] = alpha;
    ac[8 + g] = bn_beta[g] - Eu * alpha;
  }
}

// ---------------- k_o1aff: O1hf = fp16(alpha*O1 + c*vsum) ------------------
__global__ __launch_bounds__(256) void k_o1aff(const float* __restrict__ O1,
                                               const float* __restrict__ vsum,
                                               const float* __restrict__ ac,
                                               unsigned short* __restrict__ O1BF) {
  const size_t i4 = ((size_t)blockIdx.x * 256 + threadIdx.x) * 4;
  const int bg = (int)(i4 >> 16);
  const int g = bg & 7;
  const int d = (int)(i4 & 63);
  float4 a = *(const float4*)(O1 + i4);
  float4 v = *(const float4*)(vsum + (size_t)bg * DH + d);
  const float al = ac[g], cc = ac[8 + g];
  unsigned short o[4] = {f2h(al * a.x + cc * v.x), f2h(al * a.y + cc * v.y),
                         f2h(al * a.z + cc * v.z), f2h(al * a.w + cc * v.w)};
  *(uint2*)(O1BF + i4) = *(uint2*)o;
}

// ---------------- K4: out = O1hf @ w_out + b_out (fp16 MFMA) ---------------
__global__ __launch_bounds__(256) void k_out(const unsigned short* __restrict__ O1BF,
                                             const unsigned short* __restrict__ WOT,
                                             const float* __restrict__ bout,
                                             float* __restrict__ out) {
  __shared__ unsigned short sA[128][40];
  __shared__ unsigned short sB[128][40];
  const int t = threadIdx.x;
  const int col0 = blockIdx.x * 128, row0 = blockIdx.y * 128;
  const int l = t & 63, w = t >> 6;
  const int wm = (w & 1) * 64, wn = (w >> 1) * 64;
  const int lm = l & 15, lq = l >> 4;
  const int srow = t >> 1, skc = (t & 1) * 16;
  const int b = row0 >> 10;
  const int nn = (row0 + srow) & 1023;
  f32x4 acc[4][4] = {};
  for (int k0 = 0; k0 < INNER; k0 += 32) {
    {
      const int k = k0 + skc;
      const int g = k >> 6, dd = k & 63;
      const unsigned short* src = O1BF + ((size_t)(b * Hh + g) * Nn + nn) * DH + dd;
      *(uint4*)&sA[srow][skc] = *(const uint4*)src;
      *(uint4*)&sA[srow][skc + 8] = *(const uint4*)(src + 8);
    }
    {
      const unsigned short* srcB = WOT + (size_t)(col0 + srow) * INNER + k0 + skc;
      *(uint4*)&sB[srow][skc] = *(const uint4*)srcB;
      *(uint4*)&sB[srow][skc + 8] = *(const uint4*)(srcB + 8);
    }
    __syncthreads();
    f16x8 af[4], bfr[4];
#pragma unroll
    for (int i = 0; i < 4; i++) af[i] = *(const f16x8*)&sA[wm + 16 * i + lm][lq * 8];
#pragma unroll
    for (int j = 0; j < 4; j++) bfr[j] = *(const f16x8*)&sB[wn + 16 * j + lm][lq * 8];
#pragma unroll
    for (int i = 0; i < 4; i++)
#pragma unroll
      for (int j = 0; j < 4; j++) acc[i][j] = MFMA16(af[i], bfr[j], acc[i][j]);
    __syncthreads();
  }
#pragma unroll
  for (int j = 0; j < 4; j++) {
    const int col = col0 + wn + 16 * j + lm;
    const float bo = bout[col];
#pragma unroll
    for (int i = 0; i < 4; i++) {
      const int rbase = row0 + wm + 16 * i + lq * 4;
#pragma unroll
      for (int r = 0; r < 4; r++) out[(size_t)(rbase + r) * Dd + col] = acc[i][j][r] + bo;
    }
  }
}

extern "C" void kernel_launch(void* const* d_in, const int* in_sizes, int n_in,
                              void* d_out, int out_size, void* d_ws, size_t ws_size,
                              hipStream_t stream) {
  const float* x = (const float*)d_in[0];
  const float* w_qkv = (const float*)d_in[1];
  const float* conv_w = (const float*)d_in[2];
  // d_in[3] = conv_b : cancels in train-mode BN.
  const float* bn_gamma = (const float*)d_in[4];
  const float* bn_beta = (const float*)d_in[5];
  const float* w_out = (const float*)d_in[6];
  const float* b_out = (const float*)d_in[7];
  char* ws = (char*)d_ws;
  unsigned short* XB = (unsigned short*)(ws + WB_XB);
  unsigned short* QKV = (unsigned short*)(ws + WB_QKV);
  unsigned short* VT = (unsigned short*)(ws + WB_VT);
  unsigned short* SG = (unsigned short*)(ws + WB_SG);
  unsigned short* WQT = (unsigned short*)(ws + WB_WQT);
  unsigned short* WOT = (unsigned short*)(ws + WB_WOT);
  float* O1 = (float*)(ws + WB_O1);
  unsigned short* O1BF = (unsigned short*)(ws + WB_O1BF);
  float* RSUM = (float*)(ws + WB_RSUM);
  float* VSUM = (float*)(ws + WB_VSUM);
  float* STATS = (float*)(ws + WB_STATS);
  float* AC = (float*)(ws + WB_AC);

  hipMemsetAsync(STATS, 0, 64, stream);
  hipMemsetAsync(RSUM, 0, 262144, stream);
  k_xbf<<<2048, 256, 0, stream>>>(x, XB);
  k_transpose<<<dim3(48, 16), 256, 0, stream>>>(w_qkv, WQT, 512, 1536);
  k_transpose<<<dim3(16, 16), 256, 0, stream>>>(w_out, WOT, 512, 512);
  k_qkv<<<dim3(12, 64), 256, 34816, stream>>>(XB, WQT, QKV, VT);
  k_vsum<<<64, 256, 0, stream>>>(VT, VSUM);
  k_sgen<<<dim3(8, 32, 2), 512, 0, stream>>>(QKV, SG, RSUM);
  k_mixsv<<<dim3(8, 64), 512, 0, stream>>>(SG, VT, RSUM, conv_w, O1, STATS);
  k_alpha<<<1, 64, 0, stream>>>(STATS, conv_w, bn_gamma, bn_beta, AC);
  k_o1aff<<<4096, 256, 0, stream>>>(O1, VSUM, AC, O1BF);
  k_out<<<dim3(4, 64), 256, 0, stream>>>(O1BF, WOT, b_out, (float*)d_out);
}